// Round 4
// baseline (110.687 us; speedup 1.0000x reference)
//
#include <hip/hip_runtime.h>

// Sinkhorn via separable kernel: K = exp(-C/eps) = G (x) G (kron), with
// G[a][b] = exp(-100 * C1d[a][b]) read as exact 1D slices of the provided C
// (preserves reference's rounded dy^2). K.x = y-conv(G, x-conv(G, x)).
// Cost pass: K o C = H(x)G + G(x)H with H = G * C1d.
// One block per batch (32 blocks), whole chain in one kernel, state in LDS.
// Round 4 (latency-bound diagnosis): 16 waves x 3 cols (4 waves/SIMD, was 3);
// G/H pre-reordered into per-wave CONTIGUOUS padded-float4 blocks so the 48
// wave-uniform loads per step merge into pipelined s_load_dwordx8/16 instead
// of 48 scattered dwordx4 round-trips; all 12 data ds_read_b128 issued
// up-front per step (single lgkmcnt batch); scalar fmaf (pk-fma reverted).

#define SZ 48
#define SN 2304          // 48*48
#define LD 52            // padded LDS row stride (208 B, 16B-aligned)
#define NBAT 32
#define NTHR 1024        // 16 waves
#define NW 16
#define YB 3             // output cols per wave (16*3 = 48)

__global__ __launch_bounds__(256) void k_pre(const float* __restrict__ C,
                                             float* __restrict__ Gp,
                                             float* __restrict__ Hp) {
    const int idx = blockIdx.x * 256 + threadIdx.x;   // 9*256 = 2304 exactly
    const int j   = idx / SZ;
    const int col = idx - j * SZ;
    const int w   = col / 3;
    const int c   = col - w * 3;
    const float cv = C[(size_t)j * SZ * SN + (size_t)col * SZ];
    const float g  = expf(-100.f * cv);
    const int base = (w * SZ + j) * 4;
    Gp[base + c] = g;
    Hp[base + c] = g * cv;
    if (c == 0) { Gp[base + 3] = 0.f; Hp[base + 3] = 0.f; }   // pad slot
}

__global__ __launch_bounds__(NTHR) void k_sink(const float* __restrict__ pred,
                                               const float* __restrict__ tgt,
                                               const float* __restrict__ Gpg,
                                               const float* __restrict__ Hpg,
                                               float* __restrict__ out) {
    __shared__ float Fa[SZ * LD];    // alpha scaling
    __shared__ float Fb[SZ * LD];    // beta scaling (init 1)
    __shared__ float Fms[SZ * LD];   // mass_source; reused as T2t in final
    __shared__ float Fmt[SZ * LD];   // mass_target
    __shared__ float Tt[SZ * LD];    // conv intermediate, TRANSPOSED [xi][y]
    __shared__ float gsl[SZ];        // row sums of G (folded pass 0)
    __shared__ float red[32];

    const int t = threadIdx.x;
    const int b = blockIdx.x;
    const int l = t & 63;
    const int w = __builtin_amdgcn_readfirstlane(t >> 6);  // scalar wave id
    const int r0 = w * YB;                                 // wave's output cols

    const float4* __restrict__ Gp4 = (const float4*)Gpg + (size_t)w * SZ;
    const float4* __restrict__ Hp4 = (const float4*)Hpg + (size_t)w * SZ;

    // ---- init: G row sums, load channel-0 planes, sum, normalize ----
    if (t < SZ) {
        const int wc = t / 3, cc = t - wc * 3;
        float s = 0.f;
        #pragma unroll 8
        for (int j = 0; j < SZ; ++j)
            s += Gpg[(wc * SZ + j) * 4 + cc];   // G[j][t] = G[t][j]
        gsl[t] = s;
    }
    const float* __restrict__ pg = pred + (size_t)b * 3 * SN;
    const float* __restrict__ tg = tgt + (size_t)b * 3 * SN;
    float sp = 0.f, st = 0.f;
    for (int i = t; i < SN; i += NTHR) {
        const float vp = pg[i] + 1e-9f;
        const float vt = tg[i] + 1e-9f;
        const int y = i / SZ, x = i - y * SZ;
        Fms[y * LD + x] = vp;
        Fmt[y * LD + x] = vt;
        sp += vp; st += vt;
    }
    #pragma unroll
    for (int off = 32; off; off >>= 1) {
        sp += __shfl_down(sp, off);
        st += __shfl_down(st, off);
    }
    if (l == 0) { red[w] = sp; red[16 + w] = st; }
    __syncthreads();
    float ps = 0.f, ts = 0.f;
    #pragma unroll
    for (int k = 0; k < NW; ++k) { ps += red[k]; ts += red[16 + k]; }
    // folded pass 0: Fa = m_src / (gs[y]*gs[x] + 1e-6), Fb = 1
    for (int i = t; i < SN; i += NTHR) {
        const int y = i / SZ, x = i - y * SZ;
        const float ms = Fms[y * LD + x] / ps;
        Fms[y * LD + x] = ms;
        Fmt[y * LD + x] /= ts;
        Fa[y * LD + x] = ms / (gsl[y] * gsl[x] + 1e-6f);
        Fb[y * LD + x] = 1.f;
    }
    __syncthreads();

    // ---- remaining 9 half-iterations (p=1..9) ----
    for (int p = 1; p < 10; ++p) {
        float* __restrict__ src = (p & 1) ? Fa : Fb;
        float* __restrict__ dst = (p & 1) ? Fb : Fa;
        const float* __restrict__ mv = (p & 1) ? Fmt : Fms;

        // step1 (x-conv): Tt[xi][y] = sum_j G[xi][j] * src[y][j]
        if (l < SZ) {
            float4 q[12];
            #pragma unroll
            for (int jc = 0; jc < 12; ++jc)
                q[jc] = *(const float4*)&src[l * LD + jc * 4];   // batched b128
            float a0 = 0.f, a1 = 0.f, a2 = 0.f;
            #pragma unroll
            for (int j = 0; j < SZ; ++j) {
                const float4 g = Gp4[j];                          // contiguous s_load
                const float v = (j & 3) == 0 ? q[j >> 2].x
                              : (j & 3) == 1 ? q[j >> 2].y
                              : (j & 3) == 2 ? q[j >> 2].z : q[j >> 2].w;
                a0 = fmaf(g.x, v, a0);
                a1 = fmaf(g.y, v, a1);
                a2 = fmaf(g.z, v, a2);
            }
            Tt[(r0 + 0) * LD + l] = a0;
            Tt[(r0 + 1) * LD + l] = a1;
            Tt[(r0 + 2) * LD + l] = a2;
        }
        __syncthreads();

        // step2 (y-conv) + fused update: S[yi][x] = sum_j G[yi][j]*Tt[x][j]
        if (l < SZ) {
            float4 q[12];
            #pragma unroll
            for (int jc = 0; jc < 12; ++jc)
                q[jc] = *(const float4*)&Tt[l * LD + jc * 4];
            float a0 = 0.f, a1 = 0.f, a2 = 0.f;
            #pragma unroll
            for (int j = 0; j < SZ; ++j) {
                const float4 g = Gp4[j];
                const float v = (j & 3) == 0 ? q[j >> 2].x
                              : (j & 3) == 1 ? q[j >> 2].y
                              : (j & 3) == 2 ? q[j >> 2].z : q[j >> 2].w;
                a0 = fmaf(g.x, v, a0);
                a1 = fmaf(g.y, v, a1);
                a2 = fmaf(g.z, v, a2);
            }
            const float s3[3] = {a0, a1, a2};
            #pragma unroll
            for (int k = 0; k < YB; ++k) {
                const int idx = (r0 + k) * LD + l;
                const float yo = dst[idx];
                dst[idx] = mv[idx] * yo / (yo * s3[k] + 1e-6f);
            }
        }
        __syncthreads();
    }

    // ---- final: cost = sum Fa .* ((H(x)G + G(x)H) applied to Fb) ----
    // stage 1: T1t = (G-x-conv(beta))^T in Tt, T2t = (H-x-conv(beta))^T in Fms
    if (l < SZ) {
        float4 q[12];
        #pragma unroll
        for (int jc = 0; jc < 12; ++jc)
            q[jc] = *(const float4*)&Fb[l * LD + jc * 4];
        float t1[3] = {0.f, 0.f, 0.f}, t2[3] = {0.f, 0.f, 0.f};
        #pragma unroll
        for (int j = 0; j < SZ; ++j) {
            const float4 g = Gp4[j];
            const float4 h = Hp4[j];
            const float v = (j & 3) == 0 ? q[j >> 2].x
                          : (j & 3) == 1 ? q[j >> 2].y
                          : (j & 3) == 2 ? q[j >> 2].z : q[j >> 2].w;
            t1[0] = fmaf(g.x, v, t1[0]);
            t1[1] = fmaf(g.y, v, t1[1]);
            t1[2] = fmaf(g.z, v, t1[2]);
            t2[0] = fmaf(h.x, v, t2[0]);
            t2[1] = fmaf(h.y, v, t2[1]);
            t2[2] = fmaf(h.z, v, t2[2]);
        }
        #pragma unroll
        for (int k = 0; k < YB; ++k) {
            Tt [(r0 + k) * LD + l] = t1[k];
            Fms[(r0 + k) * LD + l] = t2[k];
        }
    }
    __syncthreads();

    // stage 2: U[yi][x] = sum_j H[yi][j]*T1t[x][j] + G[yi][j]*T2t[x][j]
    float part = 0.f;
    if (l < SZ) {
        float4 q1[12], q2[12];
        #pragma unroll
        for (int jc = 0; jc < 12; ++jc) {
            q1[jc] = *(const float4*)&Tt [l * LD + jc * 4];
            q2[jc] = *(const float4*)&Fms[l * LD + jc * 4];
        }
        float u[3] = {0.f, 0.f, 0.f};
        #pragma unroll
        for (int j = 0; j < SZ; ++j) {
            const float4 g = Gp4[j];
            const float4 h = Hp4[j];
            const float v1 = (j & 3) == 0 ? q1[j >> 2].x
                           : (j & 3) == 1 ? q1[j >> 2].y
                           : (j & 3) == 2 ? q1[j >> 2].z : q1[j >> 2].w;
            const float v2 = (j & 3) == 0 ? q2[j >> 2].x
                           : (j & 3) == 1 ? q2[j >> 2].y
                           : (j & 3) == 2 ? q2[j >> 2].z : q2[j >> 2].w;
            u[0] = fmaf(h.x, v1, u[0]);
            u[1] = fmaf(h.y, v1, u[1]);
            u[2] = fmaf(h.z, v1, u[2]);
            u[0] = fmaf(g.x, v2, u[0]);
            u[1] = fmaf(g.y, v2, u[1]);
            u[2] = fmaf(g.z, v2, u[2]);
        }
        #pragma unroll
        for (int k = 0; k < YB; ++k)
            part = fmaf(Fa[(r0 + k) * LD + l], u[k], part);
    }
    #pragma unroll
    for (int off = 32; off; off >>= 1) part += __shfl_down(part, off);
    if (l == 0) red[w] = part;
    __syncthreads();
    if (t == 0) {
        float c = 0.f;
        #pragma unroll
        for (int k = 0; k < NW; ++k) c += red[k];
        out[b] = c;
    }
}

extern "C" void kernel_launch(void* const* d_in, const int* in_sizes, int n_in,
                              void* d_out, int out_size, void* d_ws, size_t ws_size,
                              hipStream_t stream) {
    const float* pred = (const float*)d_in[0];
    const float* tgt  = (const float*)d_in[1];
    const float* C    = (const float*)d_in[2];
    float* Gp = (float*)d_ws;          // 16*48*4 = 3072 floats
    float* Hp = Gp + NW * SZ * 4;      // 3072 floats

    k_pre<<<9, 256, 0, stream>>>(C, Gp, Hp);
    k_sink<<<NBAT, NTHR, 0, stream>>>(pred, tgt, Gp, Hp, (float*)d_out);
}